// Round 16
// baseline (168.409 us; speedup 1.0000x reference)
//
#include <hip/hip_runtime.h>
#include <hip/hip_bf16.h>

#define BB 2
#define LL 2048
#define DD 256
#define PP 32
#define PX 64            // 2*P channels (cos|sin)
#define NROW (BB*LL)     // 4096
#define COLS 1440
#define KIN 288
#define CC 64            // attention chunk
#define NC (LL/CC)       // 32
#define PI_F 3.14159265358979323846f

typedef __attribute__((ext_vector_type(8))) short bf16x8;
typedef __attribute__((ext_vector_type(4))) float f32x4;

__device__ __forceinline__ float gelu_f(float v){
    return 0.5f*v*(1.0f+erff(v*0.70710678118654752440f));
}
__device__ __forceinline__ float sigm_f(float v){
    return 1.0f/(1.0f+expf(-v));
}
__device__ __forceinline__ short f2b(float v){
    __hip_bfloat16 h = __float2bfloat16(v);
    return *reinterpret_cast<short*>(&h);
}
__device__ __forceinline__ float b2f(unsigned short u){
    unsigned int x = ((unsigned int)u)<<16;
    return __uint_as_float(x);
}

// ---------------- kprep: all weight prep + input bf16 staging (fused) ----------------
__global__ void kprep(const float* w_content,const float* w_val,const float* w_ctx,
                      const float* w_cpe,const float* sg_w1,const float* hop_w1,
                      const float* b_content,const float* b_val,const float* b_ctx,
                      const float* b_cpe,const float* sg_b1,const float* hop_b1,
                      const float* pos_phases,const float* kv_w1,const float* kv_w2,
                      const float* hop_w2,const float* w_out,const float* x,
                      short* W_catb,float* bias_cat,float* w2mem,
                      short* kvw1b,short* kvw2b,float* hop_w2T,short* w_outb,
                      short* Xb,short* Xin2b){
    int idx = blockIdx.x*256 + threadIdx.x;
    int n1 = COLS*KIN;
    if (idx < n1){
        int row = idx / KIN, k = idx % KIN;
        float v = 0.f;
        if      (row < 256){ if (k<256) v = w_content[row*256+k]; }
        else if (row < 512){ if (k<256) v = w_val[(row-256)*256+k]; }
        else if (row < 768){ if (k<256) v = w_ctx[(row-512)*256+k]; }
        else if (row < 800){ if (k<256) v = w_cpe[(row-768)*256+k]; }
        else if (row < 928){ if (k<256) v = sg_w1[(row-800)*256+k]; }
        else               { v = hop_w1[(row-928)*288 + k]; }
        W_catb[idx] = f2b(v);
        return;
    }
    idx -= n1;
    if (idx < COLS){
        int row = idx; float v = 0.f;
        if      (row < 256) v = b_content[row];
        else if (row < 512) v = b_val[row-256];
        else if (row < 768) v = b_ctx[row-512];
        else if (row < 800) v = b_cpe[row-768];
        else if (row < 928) v = sg_b1[row-800];
        else                v = hop_b1[row-928];
        bias_cat[row] = v;
        return;
    }
    idx -= COLS;
    if (idx < LL*PP){
        int l = idx/PP, p = idx%PP;
        float ph = pos_phases[l*PP+p];
        w2mem[l*PX+p]     = cosf(ph);
        w2mem[l*PX+32+p]  = sinf(ph);
        return;
    }
    idx -= LL*PP;
    if (idx < 256*512){ kvw1b[idx] = f2b(kv_w1[idx]); return; }
    idx -= 256*512;
    if (idx < 32*256){ kvw2b[idx] = f2b(kv_w2[idx]); return; }
    idx -= 32*256;
    if (idx < 128*132){
        int k=idx/132, o=idx%132;
        hop_w2T[idx] = hop_w2[o*128+k];
        return;
    }
    idx -= 128*132;
    if (idx < 256*256){ w_outb[idx] = f2b(w_out[idx]); return; }
    idx -= 256*256;
    if (idx < NROW*KIN){
        int r = idx / KIN, d = idx % KIN;
        float v;
        if (d < 256){ v = x[(size_t)r*DD + d]; Xin2b[(size_t)r*512 + d] = f2b(v); }
        else          v = pos_phases[(r % LL)*PP + (d-256)];
        Xb[idx] = f2b(v);
    }
}

// ---------------- kA_gemm: MFMA bf16  Yb[4096][1440](bf16) = Xb @ W_catb^T ----------------
__global__ __launch_bounds__(256) void kA_gemm(const short* Xb,const short* Wb,short* Yb){
    int t=threadIdx.x;
    int wid=t>>6, l=t&63;
    int q=blockIdx.x;
    int ct=q%15, rt=q/15;
    int r0=rt*64 + wid*16;
    int c0=ct*96;
    int lr=l&15, lk=(l>>4)*8;
    const short* ap = Xb + (size_t)(r0+lr)*KIN + lk;
    const short* bp = Wb + (size_t)(c0+lr)*KIN + lk;
    f32x4 acc[6];
    #pragma unroll
    for (int f=0;f<6;f++) acc[f]=(f32x4){0.f,0.f,0.f,0.f};
    for (int ks=0;ks<9;ks++){
        bf16x8 a = *(const bf16x8*)(ap + ks*32);
        #pragma unroll
        for (int f=0;f<6;f++){
            bf16x8 b = *(const bf16x8*)(bp + (size_t)f*16*KIN + ks*32);
            acc[f] = __builtin_amdgcn_mfma_f32_16x16x32_bf16(a,b,acc[f],0,0,0);
        }
    }
    int orow = r0 + (l>>4)*4;
    int ocol = c0 + lr;
    #pragma unroll
    for (int f=0;f<6;f++){
        #pragma unroll
        for (int qq=0;qq<4;qq++){
            Yb[(size_t)(orow+qq)*COLS + ocol + 16*f] = f2b(acc[f][qq]);
        }
    }
}

// ---------------- kA_post: 4 rows/block, bf16 content/gated_v out, + ctx partial sums ----------------
__global__ __launch_bounds__(256,4) void kA_post(const short* Yb,const float* bias_cat,
        const float* sg_w2,const float* sg_b2,
        const float* hop_w2T,const float* hop_b2,const float* pos_phases,
        short* contentb,short* gatedvb,float* ctx,float* ctxps,float* key_ph,
        float* store_gate,float* coef_mem){
    __shared__ float yb[4][1448];
    __shared__ float red[4][32];
    __shared__ float offb[4][136];
    __shared__ float scl[4][4];
    __shared__ float sgvv[4];
    int t=threadIdx.x;
    int r0=blockIdx.x*4;
    {
        const ushort4* Yu4 = (const ushort4*)(Yb) + (size_t)r0*360;
        #pragma unroll
        for (int i=0;i<6;i++){
            int chunk=i*256+t;
            if (chunk<1440){
                int r=chunk/360, c=(chunk%360)*4;
                ushort4 s4 = Yu4[chunk];
                float4 bc = *(const float4*)&bias_cat[c];
                yb[r][c+0]=b2f(s4.x)+bc.x;
                yb[r][c+1]=b2f(s4.y)+bc.y;
                yb[r][c+2]=b2f(s4.z)+bc.z;
                yb[r][c+3]=b2f(s4.w)+bc.w;
            }
        }
    }
    __syncthreads();
    #pragma unroll
    for (int r=0;r<4;r++){
        contentb[(size_t)(r0+r)*DD+t] = f2b(yb[r][t]);
        ctx[(size_t)(r0+r)*DD+t]      = yb[r][512+t];
    }
    // per-block ctx partial sum (replaces k3a)
    ctxps[(size_t)blockIdx.x*DD + t] = (yb[0][512+t]+yb[1][512+t])+(yb[2][512+t]+yb[3][512+t]);
    #pragma unroll
    for (int j=0;j<8;j++){
        int idx=j*256+t, r=idx>>9, g=idx&511;
        yb[r][928+g] = gelu_f(yb[r][928+g]);
    }
    if (t<128){
        int r=t>>5, j=t&31;
        float s=0.f;
        #pragma unroll
        for (int k=0;k<4;k++){
            int jj=j+32*k;
            s += gelu_f(yb[r][800+jj])*sg_w2[jj];
        }
        red[r][j]=s;
        key_ph[(size_t)(r0+r)*PP+j] = tanhf(yb[r][768+j])*PI_F;
    }
    __syncthreads();
    if (t<128){
        int r=t>>5;
        float s=red[r][t&31];
        #pragma unroll
        for (int off=16;off>=1;off>>=1) s += __shfl_down(s,off,32);
        if ((t&31)==0){
            float g=sigm_f(s+sg_b2[0]);
            sgvv[r]=g;
            store_gate[r0+r]=g;
        }
    }
    for (int sIdx=t; sIdx<528; sIdx+=256){
        int r=sIdx/132, o=sIdx%132, h=o/33;
        const float* yh=&yb[r][928+h*128];
        float a0=0.f,a1=0.f,a2=0.f,a3=0.f;
        #pragma unroll 8
        for (int k=0;k<128;k+=4){
            a0 += hop_w2T[(size_t)(k+0)*132+o]*yh[k+0];
            a1 += hop_w2T[(size_t)(k+1)*132+o]*yh[k+1];
            a2 += hop_w2T[(size_t)(k+2)*132+o]*yh[k+2];
            a3 += hop_w2T[(size_t)(k+3)*132+o]*yh[k+3];
        }
        offb[r][o]=a0+a1+a2+a3+hop_b2[o];
    }
    __syncthreads();
    #pragma unroll
    for (int r=0;r<4;r++) gatedvb[(size_t)(r0+r)*DD+t]=f2b(yb[r][256+t]*sgvv[r]);
    if (t<16){
        int r=t>>2, h=t&3;
        const float c01=0.99500416527802576610f;  // cos(0.1)
        const float c02=0.98006657784124163112f;  // cos(0.2)
        float ww=sigm_f(offb[r][h*33+32])*2.0f+0.1f;
        float iw=1.0f/(ww*ww+1e-6f);
        float w1=expf(-0.5f*iw);
        float w2=expf(-2.0f*iw);
        float tot=1.0f+2.0f*w1+2.0f*w2;
        float Wc =1.0f+2.0f*w1*c01+2.0f*w2*c02;
        scl[r][h]=Wc/((tot+1e-6f)*5.65685424949238019520f*4.0f); // /(sqrt(P)*H)
    }
    __syncthreads();
    if (t<128){
        int r=t>>5, p=t&31;
        int l=(r0+r)%LL;
        float ppv=pos_phases[l*PP+p];
        float ca=0.f, sb=0.f;
        #pragma unroll
        for (int h=0;h<4;h++){
            float center=tanhf(offb[r][h*33+p])*PI_F;
            float ang=ppv+center;
            float sc=scl[r][h];
            ca+=sc*cosf(ang);
            sb+=sc*sinf(ang);
        }
        coef_mem[(size_t)(r0+r)*PX+p]=ca;
        coef_mem[(size_t)(r0+r)*PX+32+p]=sb;
    }
}

// ---------------- k3c: ctx_avg (prefix from ctxps partials; reg-ILP scan; writes bf16 Xin2b) ----------------
__global__ void k3c_ctxavg(const float* ctx,const float* ctxps,short* Xin2b){
    int t=threadIdx.x;
    int bi=blockIdx.x;
    int c=bi%NC, b=bi/NC;
    // prefix of earlier chunks from 4-row partial sums (16 partials per chunk)
    int nj=16*c;
    const float* pp = ctxps + (size_t)(b*512)*DD + t;
    float s0=0.f,s1=0.f,s2=0.f,s3=0.f;
    int j=0;
    for (; j+3<nj; j+=4){
        s0+=pp[(size_t)(j+0)*DD];
        s1+=pp[(size_t)(j+1)*DD];
        s2+=pp[(size_t)(j+2)*DD];
        s3+=pp[(size_t)(j+3)*DD];
    }
    for (; j<nj; j++) s0+=pp[(size_t)j*DD];
    float run=(s0+s1)+(s2+s3);
    float v[CC];
    #pragma unroll
    for (int i=0;i<CC;i++) v[i]=ctx[((size_t)b*LL + c*CC + i)*DD + t];
    #pragma unroll
    for (int i=0;i<CC;i++){
        int l = c*CC+i;
        run += v[i];
        Xin2b[((size_t)b*LL+l)*512 + 256 + t] = f2b(run/(float)(l+1));
    }
}

// ---------------- kmid: k3d1 (blocks 0..255) + kgate (blocks 256..319) ----------------
__global__ __launch_bounds__(256) void kmid(const short* Xin2b,const short* kvw1b,
        const float* kv_b1, short* Hb,
        const float* store_gate,const float* key_ph,float* coefkv){
    __shared__ float sh[2048];
    __shared__ float red[256];
    __shared__ float rsgS[64];
    int t=threadIdx.x;
    if (blockIdx.x < 256){
        // k3d1: kv MLP layer 1 (MFMA) -> gelu -> bf16 Hb
        int wid=t>>6, l=t&63;
        int q=blockIdx.x;
        int nt=q&3, mt=q>>2;
        int r0=mt*64 + wid*16;
        int c0=nt*64;
        int lr=l&15, lk=(l>>4)*8;
        const short* ap = Xin2b + (size_t)(r0+lr)*512 + lk;
        const short* bp = kvw1b + (size_t)(c0+lr)*512 + lk;
        f32x4 acc[4];
        #pragma unroll
        for (int f=0;f<4;f++) acc[f]=(f32x4){0.f,0.f,0.f,0.f};
        for (int ks=0;ks<16;ks++){
            bf16x8 a = *(const bf16x8*)(ap + ks*32);
            #pragma unroll
            for (int f=0;f<4;f++){
                bf16x8 b = *(const bf16x8*)(bp + (size_t)f*16*512 + ks*32);
                acc[f] = __builtin_amdgcn_mfma_f32_16x16x32_bf16(a,b,acc[f],0,0,0);
            }
        }
        int orow = r0 + (l>>4)*4;
        #pragma unroll
        for (int f=0;f<4;f++){
            int oc = c0 + lr + 16*f;
            float bias = kv_b1[oc];
            #pragma unroll
            for (int qq=0;qq<4;qq++){
                Hb[(size_t)(orow+qq)*256 + oc] = f2b(gelu_f(acc[f][qq]+bias));
            }
        }
        return;
    }
    // kgate
    int q=blockIdx.x-256;
    int c=q&31, b=q>>5;
    int n=(c+1)*CC;
    for (int i=t;i<n;i+=256) sh[i]=store_gate[(size_t)b*LL+i];
    __syncthreads();
    float p=0.f;
    for (int i=t;i<c*CC;i+=256) p+=sh[i];
    red[t]=p;
    __syncthreads();
    for (int off=128;off>=1;off>>=1){
        if (t<off) red[t]+=red[t+off];
        __syncthreads();
    }
    float S0=red[0];
    if (t<64){
        float s=sh[c*CC+t];
        #pragma unroll
        for (int off=1;off<64;off<<=1){
            float v=__shfl_up(s,off);
            if (t>=off) s+=v;
        }
        rsgS[t]=rsqrtf(fmaxf(S0+s,1.0f)*32.0f);
    }
    __syncthreads();
    #pragma unroll
    for (int j=0;j<8;j++){
        int g2=t+j*256;             // 64 rows * 32 p
        int l=g2>>5, pp=g2&31;
        float a=key_ph[((size_t)b*LL + c*CC + l)*PP + pp];
        float rv=rsgS[l];
        coefkv[((size_t)b*LL + c*CC + l)*PX + pp]      = cosf(a)*rv;
        coefkv[((size_t)b*LL + c*CC + l)*PX + 32 + pp] = sinf(a)*rv;
    }
}

// ---------------- k3d2: kv MLP layer 2 (MFMA) -> tanh -> cos/sin w2kv ----------------
__global__ __launch_bounds__(256) void k3d2(const short* Hb,const short* kvw2b,
        const float* kv_b2, float* w2kv){
    int t=threadIdx.x;
    int wid=t>>6, l=t&63;
    int mt=blockIdx.x;             // 64 blocks
    int r0=mt*64 + wid*16;
    int lr=l&15, lk=(l>>4)*8;
    const short* ap = Hb + (size_t)(r0+lr)*256 + lk;
    const short* bp = kvw2b + (size_t)lr*256 + lk;
    f32x4 acc0=(f32x4){0.f,0.f,0.f,0.f};
    f32x4 acc1=(f32x4){0.f,0.f,0.f,0.f};
    for (int ks=0;ks<8;ks++){
        bf16x8 a  = *(const bf16x8*)(ap + ks*32);
        bf16x8 b0 = *(const bf16x8*)(bp + ks*32);
        bf16x8 b1 = *(const bf16x8*)(bp + (size_t)16*256 + ks*32);
        acc0 = __builtin_amdgcn_mfma_f32_16x16x32_bf16(a,b0,acc0,0,0,0);
        acc1 = __builtin_amdgcn_mfma_f32_16x16x32_bf16(a,b1,acc1,0,0,0);
    }
    int orow=r0+(l>>4)*4;
    #pragma unroll
    for (int f=0;f<2;f++){
        int p = lr + 16*f;
        float bias = kv_b2[p];
        f32x4 av = f? acc1:acc0;
        #pragma unroll
        for (int qq=0;qq<4;qq++){
            float sp=tanhf(av[qq]+bias)*PI_F;
            w2kv[(size_t)(orow+qq)*PX + p]    = cosf(sp);
            w2kv[(size_t)(orow+qq)*PX + 32+p] = sinf(sp);
        }
    }
}

// ---------------- k4: per-chunk outer-product sums (d-split, bf16 val, both inst) ----------------
__global__ __launch_bounds__(256) void k4_chunksum(
        const short* valA,const float* w2A,int w2bA,
        const short* valB,const float* w2B,int w2bB,
        float* CS){
    __shared__ float w2s[CC][PX];    // 16 KB
    int t=threadIdx.x, q=blockIdx.x;
    int dq=q&3, c=(q>>2)&31, b=(q>>7)&1, inst=q>>8;
    const short* val = inst? valB:valA;
    const float* w2  = inst? w2B:w2A;
    int w2b          = inst? w2bB:w2bA;
    for (int i=0;i<16;i++){
        int idx=i*256+t;
        int l=idx>>6, p=idx&63;
        w2s[l][p]=w2[(size_t)w2b*b + (size_t)(c*CC+l)*PX + p];
    }
    __syncthreads();
    int d=t&63, pg=t>>6;
    float acc[16];
    #pragma unroll
    for (int j=0;j<16;j++) acc[j]=0.f;
    const short* vp = val + ((size_t)b*LL + c*CC)*DD + dq*64 + d;
    for (int l=0;l<CC;l++){
        float v = b2f((unsigned short)vp[(size_t)l*DD]);
        const float4* wr=(const float4*)&w2s[l][pg*16];
        #pragma unroll
        for (int k=0;k<4;k++){
            float4 w=wr[k];
            acc[4*k]   += w.x*v;
            acc[4*k+1] += w.y*v;
            acc[4*k+2] += w.z*v;
            acc[4*k+3] += w.w*v;
        }
    }
    float* cp = CS + (((size_t)(inst*BB+b)*NC + c)*PX + pg*16)*DD + dq*64 + d;
    #pragma unroll
    for (int j=0;j<16;j++) cp[(size_t)j*DD]=acc[j];
}

// ---------------- k5: exclusive prefix over chunks -> bf16 PFXb (ILP loads) ----------------
__global__ void k5_prefix(const float* CS,short* PFXb){
    int g=blockIdx.x*256+threadIdx.x;   // 2*BB*PX*DD = 65536 threads
    int d=g&255, p2=(g>>8)&63, b=(g>>14)&1, inst=g>>15;
    size_t base=(((size_t)(inst*BB+b)*NC)*PX+p2)*DD+d;
    float v[NC];
    #pragma unroll
    for (int c=0;c<NC;c++) v[c]=CS[base+(size_t)c*PX*DD];
    float run=0.f;
    #pragma unroll
    for (int c=0;c<NC;c++){
        PFXb[base+(size_t)c*PX*DD]=f2b(run);
        run+=v[c];
    }
}

// ---------------- k6: prefix-GEMM + diagonal causal tile (d-split, bf16 val/pfx) ----------------
__global__ __launch_bounds__(256) void k6_attn(
        const float* coefA,const float* w2A,int w2bA,const short* valA,float* outA,
        const float* coefB,const float* w2B,int w2bB,const short* valB,float* outB,
        const short* PFXb){
    __shared__ float coefs[CC][PX+1];
    __shared__ float w2s[CC][PX];
    __shared__ float S[CC][CC+1];
    int t=threadIdx.x, q=blockIdx.x;
    int dq=q&3, qc=(q>>2)&31, b=(q>>7)&1, inst=q>>8;
    const float* coef = inst? coefB:coefA;
    const float* w2   = inst? w2B:w2A;
    int w2b           = inst? w2bB:w2bA;
    const short* val  = inst? valB:valA;
    float* out        = inst? outB:outA;
    int d0 = dq*64;
    for (int i=0;i<16;i++){
        int idx=i*256+t;
        int l=idx>>6, p=idx&63;
        coefs[l][p]=coef[((size_t)b*LL + qc*CC + l)*PX + p];
        w2s[l][p]  =w2[(size_t)w2b*b + (size_t)(qc*CC+l)*PX + p];
    }
    __syncthreads();
    // diagonal score tile S[l][lp], causal lp<=l
    {
        int l=t&63, lpb=(t>>6)*16;
        float cf[PX];
        #pragma unroll
        for (int p=0;p<PX;p++) cf[p]=coefs[l][p];
        for (int qq=0;qq<16;qq++){
            int lp=lpb+qq;
            float s=0.f;
            if (lp<=l){
                const float4* wr=(const float4*)&w2s[lp][0];
                #pragma unroll
                for (int k=0;k<16;k++){
                    float4 w=wr[k];
                    s += w.x*cf[4*k]+w.y*cf[4*k+1]+w.z*cf[4*k+2]+w.w*cf[4*k+3];
                }
            }
            S[l][lp]=s;
        }
    }
    __syncthreads();
    // prefix-GEMM (previous chunks, bf16 pfx) + in-chunk PV
    {
        int d=t&63, lq=t>>6;             // 4 q-groups x 16 rows, 64 d each
        float acc[16];
        #pragma unroll
        for (int i=0;i<16;i++) acc[i]=0.f;
        const short* pfx = PFXb + (((size_t)(inst*BB+b)*NC + qc)*PX)*DD + d0 + d;
        for (int p=0;p<PX;p++){
            float pf = b2f((unsigned short)pfx[(size_t)p*DD]);
            #pragma unroll
            for (int i=0;i<16;i++) acc[i] += coefs[lq*16+i][p]*pf;
        }
        const short* vptr = val + ((size_t)b*LL + qc*CC)*DD + d0 + d;
        int kmax = lq*16+16;
        for (int lp=0; lp<kmax; lp++){
            float v = b2f((unsigned short)vptr[(size_t)lp*DD]);
            #pragma unroll
            for (int i=0;i<16;i++) acc[i] += S[lq*16+i][lp]*v;
        }
        float* op = out + ((size_t)b*LL + qc*CC + lq*16)*DD + d0 + d;
        #pragma unroll
        for (int i=0;i<16;i++) op[(size_t)i*DD] = acc[i];
    }
}

// ---------------- k7: LN + MFMA output GEMM + residual, write FLOAT32 ----------------
__global__ __launch_bounds__(256) void k7_final(const float* comb,const float* kvout,
        const float* x,const float* ln_g,const float* ln_b,const short* w_outb,const float* b_out,
        float* out){
    __shared__ float cb[16][260];
    __shared__ short Ab[16][264];
    __shared__ float red[16][32];
    __shared__ float mvm[16][2];
    int t=threadIdx.x, r0=blockIdx.x*16;
    #pragma unroll
    for (int i=0;i<16;i++){
        int idx=i*256+t;
        int r=idx>>8, c=idx&255;
        cb[r][c]=comb[(size_t)(r0+r)*DD+c]+kvout[(size_t)(r0+r)*DD+c];
    }
    __syncthreads();
    {
        int r=t>>4, j=t&15;
        float s=0.f,s2=0.f;
        #pragma unroll
        for (int k=0;k<16;k++){
            float v=cb[r][j+16*k];
            s+=v; s2+=v*v;
        }
        red[r][j]=s; red[r][16+j]=s2;
    }
    __syncthreads();
    if (t<16){
        float s=0.f,s2=0.f;
        #pragma unroll
        for (int j=0;j<16;j++){ s+=red[t][j]; s2+=red[t][16+j]; }
        float mu=s/256.f;
        float var=s2/256.f-mu*mu;
        mvm[t][0]=mu; mvm[t][1]=rsqrtf(var+1e-5f);
    }
    __syncthreads();
    #pragma unroll
    for (int i=0;i<16;i++){
        int idx=i*256+t;
        int r=idx>>8, c=idx&255;
        Ab[r][c]=f2b((cb[r][c]-mvm[r][0])*mvm[r][1]*ln_g[c]+ln_b[c]);
    }
    __syncthreads();
    int wid=t>>6, l=t&63;
    int lr=l&15, lk=(l>>4)*8;
    f32x4 acc[4];
    #pragma unroll
    for (int f=0;f<4;f++) acc[f]=(f32x4){0.f,0.f,0.f,0.f};
    for (int ks=0;ks<8;ks++){
        bf16x8 a = *(const bf16x8*)&Ab[lr][lk+ks*32];
        #pragma unroll
        for (int f=0;f<4;f++){
            bf16x8 bv = *(const bf16x8*)(w_outb + (size_t)(wid*64+f*16+lr)*256 + lk + ks*32);
            acc[f] = __builtin_amdgcn_mfma_f32_16x16x32_bf16(a,bv,acc[f],0,0,0);
        }
    }
    int orow = r0 + (l>>4)*4;
    #pragma unroll
    for (int f=0;f<4;f++){
        int oc = wid*64 + f*16 + lr;
        float bo = b_out[oc];
        #pragma unroll
        for (int qq=0;qq<4;qq++){
            out[(size_t)(orow+qq)*DD + oc] = x[(size_t)(orow+qq)*DD + oc] + acc[f][qq] + bo;
        }
    }
}

extern "C" void kernel_launch(void* const* d_in, const int* in_sizes, int n_in,
                              void* d_out, int out_size, void* d_ws, size_t ws_size,
                              hipStream_t stream){
    (void)in_sizes; (void)n_in; (void)out_size; (void)ws_size;
    const float* x         =(const float*)d_in[0];
    const float* pos_phases=(const float*)d_in[1];
    const float* w_content =(const float*)d_in[2];
    const float* b_content =(const float*)d_in[3];
    const float* hop_w1    =(const float*)d_in[4];
    const float* hop_b1    =(const float*)d_in[5];
    const float* hop_w2    =(const float*)d_in[6];
    const float* hop_b2    =(const float*)d_in[7];
    const float* w_cpe     =(const float*)d_in[8];
    const float* b_cpe     =(const float*)d_in[9];
    const float* w_val     =(const float*)d_in[10];
    const float* b_val     =(const float*)d_in[11];
    const float* w_ctx     =(const float*)d_in[12];
    const float* b_ctx     =(const float*)d_in[13];
    const float* kv_w1     =(const float*)d_in[14];
    const float* kv_b1     =(const float*)d_in[15];
    const float* kv_w2     =(const float*)d_in[16];
    const float* kv_b2     =(const float*)d_in[17];
    const float* sg_w1     =(const float*)d_in[18];
    const float* sg_b1     =(const float*)d_in[19];
    const float* sg_w2     =(const float*)d_in[20];
    const float* sg_b2     =(const float*)d_in[21];
    const float* ln_g      =(const float*)d_in[22];
    const float* ln_b      =(const float*)d_in[23];
    const float* w_out     =(const float*)d_in[24];
    const float* b_out     =(const float*)d_in[25];

    float* ws=(float*)d_ws;
    size_t o=0;
    short* W_catb  =(short*)(ws+o); o+=(size_t)COLS*KIN/2;
    short* Xb      =(short*)(ws+o); o+=(size_t)NROW*KIN/2;
    short* kvw1b   =(short*)(ws+o); o+=(size_t)256*512/2;
    short* kvw2b   =(short*)(ws+o); o+=(size_t)32*256/2;
    short* w_outb  =(short*)(ws+o); o+=(size_t)256*256/2;
    short* Hb      =(short*)(ws+o); o+=(size_t)NROW*256/2;
    short* contentb=(short*)(ws+o); o+=(size_t)NROW*DD/2;
    short* gatedvb =(short*)(ws+o); o+=(size_t)NROW*DD/2;
    short* PFXb    =(short*)(ws+o); o+=(size_t)2*BB*NC*PX*DD/2;
    float* bias_cat=ws+o; o+=COLS;
    float* hop_w2T =ws+o; o+=(size_t)128*132;
    float* w2mem   =ws+o; o+=(size_t)LL*PX;
    float* ctx     =ws+o; o+=(size_t)NROW*DD;      // dead after k3c -> comb
    float* xin2_kv =ws+o; o+=(size_t)NROW*DD;      // Xin2b (bf16) then kvout (f32)
    float* key_ph  =ws+o; o+=(size_t)NROW*PP;
    float* store_gate=ws+o; o+=NROW;
    float* coef_mem=ws+o; o+=(size_t)NROW*PX;
    float* coefkv  =ws+o; o+=(size_t)NROW*PX;
    float* w2kv    =ws+o; o+=(size_t)NROW*PX;
    float* ctxps   =ws+o; o+=(size_t)(NROW/4)*DD;  // 1 MB: per-4-row ctx partial sums
    float* CS      =ws+o; o+=(size_t)2*BB*NC*PX*DD;  // 16.8 MB; Yb (bf16) aliases it
    short* Yb      =(short*)CS;          // Yb dead before k4 writes CS
    short* Xin2b   =(short*)xin2_kv;     // written kprep/k3c, read kmid (before k6)
    float* comb  = ctx;
    float* kvout = xin2_kv;              // written k6, read k7

    int prep_total = COLS*KIN + COLS + LL*PP + 256*512 + 32*256 + 128*132 + 256*256 + NROW*KIN;
    kprep<<<(prep_total+255)/256,256,0,stream>>>(
                                 w_content,w_val,w_ctx,w_cpe,sg_w1,hop_w1,
                                 b_content,b_val,b_ctx,b_cpe,sg_b1,hop_b1,
                                 pos_phases,kv_w1,kv_w2,hop_w2,w_out,x,
                                 W_catb,bias_cat,w2mem,kvw1b,kvw2b,hop_w2T,w_outb,Xb,Xin2b);
    kA_gemm<<<960,256,0,stream>>>(Xb,W_catb,Yb);
    kA_post<<<NROW/4,256,0,stream>>>(Yb,bias_cat,sg_w2,sg_b2,hop_w2T,hop_b2,pos_phases,
                                     contentb,gatedvb,ctx,ctxps,key_ph,store_gate,coef_mem);
    k3c_ctxavg<<<BB*NC,256,0,stream>>>(ctx,ctxps,Xin2b);
    kmid<<<256+BB*NC,256,0,stream>>>(Xin2b,kvw1b,kv_b1,Hb,store_gate,key_ph,coefkv);
    k3d2<<<64,256,0,stream>>>(Hb,kvw2b,kv_b2,w2kv);
    k4_chunksum<<<2*BB*NC*4,256,0,stream>>>(contentb,w2mem,0,
                                            gatedvb,w2kv,LL*PX,CS);
    k5_prefix<<<2*BB*PX*DD/256,256,0,stream>>>(CS,PFXb);
    k6_attn<<<2*BB*NC*4,256,0,stream>>>(coef_mem,w2mem,0,contentb,comb,
                                        coefkv,w2kv,LL*PX,gatedvb,kvout,PFXb);
    k7_final<<<NROW/16,256,0,stream>>>(comb,kvout,x,ln_g,ln_b,w_outb,b_out,
                                       (float*)d_out);
}

// Round 17
// 146.335 us; speedup vs baseline: 1.1508x; 1.1508x over previous
//
#include <hip/hip_runtime.h>
#include <hip/hip_bf16.h>

#define BB 2
#define LL 2048
#define DD 256
#define PP 32
#define PX 64            // 2*P channels (cos|sin)
#define NROW (BB*LL)     // 4096
#define COLS 1440
#define KIN 288
#define CC 64            // attention chunk
#define NC (LL/CC)       // 32
#define PI_F 3.14159265358979323846f

typedef __attribute__((ext_vector_type(8))) short bf16x8;
typedef __attribute__((ext_vector_type(4))) float f32x4;

__device__ __forceinline__ float gelu_f(float v){
    return 0.5f*v*(1.0f+erff(v*0.70710678118654752440f));
}
__device__ __forceinline__ float sigm_f(float v){
    return 1.0f/(1.0f+expf(-v));
}
__device__ __forceinline__ short f2b(float v){
    __hip_bfloat16 h = __float2bfloat16(v);
    return *reinterpret_cast<short*>(&h);
}
__device__ __forceinline__ float b2f(unsigned short u){
    unsigned int x = ((unsigned int)u)<<16;
    return __uint_as_float(x);
}

// ---------------- kprep: all weight prep + input bf16 staging (fused) ----------------
__global__ void kprep(const float* w_content,const float* w_val,const float* w_ctx,
                      const float* w_cpe,const float* sg_w1,const float* hop_w1,
                      const float* b_content,const float* b_val,const float* b_ctx,
                      const float* b_cpe,const float* sg_b1,const float* hop_b1,
                      const float* pos_phases,const float* kv_w1,const float* kv_w2,
                      const float* hop_w2,const float* w_out,const float* x,
                      short* W_catb,float* bias_cat,float* w2mem,
                      short* kvw1b,short* kvw2b,float* hop_w2T,short* w_outb,
                      short* Xb,short* Xin2b){
    int idx = blockIdx.x*256 + threadIdx.x;
    int n1 = COLS*KIN;
    if (idx < n1){
        int row = idx / KIN, k = idx % KIN;
        float v = 0.f;
        if      (row < 256){ if (k<256) v = w_content[row*256+k]; }
        else if (row < 512){ if (k<256) v = w_val[(row-256)*256+k]; }
        else if (row < 768){ if (k<256) v = w_ctx[(row-512)*256+k]; }
        else if (row < 800){ if (k<256) v = w_cpe[(row-768)*256+k]; }
        else if (row < 928){ if (k<256) v = sg_w1[(row-800)*256+k]; }
        else               { v = hop_w1[(row-928)*288 + k]; }
        W_catb[idx] = f2b(v);
        return;
    }
    idx -= n1;
    if (idx < COLS){
        int row = idx; float v = 0.f;
        if      (row < 256) v = b_content[row];
        else if (row < 512) v = b_val[row-256];
        else if (row < 768) v = b_ctx[row-512];
        else if (row < 800) v = b_cpe[row-768];
        else if (row < 928) v = sg_b1[row-800];
        else                v = hop_b1[row-928];
        bias_cat[row] = v;
        return;
    }
    idx -= COLS;
    if (idx < LL*PP){
        int l = idx/PP, p = idx%PP;
        float ph = pos_phases[l*PP+p];
        w2mem[l*PX+p]     = cosf(ph);
        w2mem[l*PX+32+p]  = sinf(ph);
        return;
    }
    idx -= LL*PP;
    if (idx < 256*512){ kvw1b[idx] = f2b(kv_w1[idx]); return; }
    idx -= 256*512;
    if (idx < 32*256){ kvw2b[idx] = f2b(kv_w2[idx]); return; }
    idx -= 32*256;
    if (idx < 128*132){
        int k=idx/132, o=idx%132;
        hop_w2T[idx] = hop_w2[o*128+k];
        return;
    }
    idx -= 128*132;
    if (idx < 256*256){ w_outb[idx] = f2b(w_out[idx]); return; }
    idx -= 256*256;
    if (idx < NROW*KIN){
        int r = idx / KIN, d = idx % KIN;
        float v;
        if (d < 256){ v = x[(size_t)r*DD + d]; Xin2b[(size_t)r*512 + d] = f2b(v); }
        else          v = pos_phases[(r % LL)*PP + (d-256)];
        Xb[idx] = f2b(v);
    }
}

// ---------------- kA_gemm: MFMA bf16  Yb[4096][1440](bf16) = Xb @ W_catb^T ----------------
__global__ __launch_bounds__(256) void kA_gemm(const short* Xb,const short* Wb,short* Yb){
    int t=threadIdx.x;
    int wid=t>>6, l=t&63;
    int q=blockIdx.x;
    int ct=q%15, rt=q/15;
    int r0=rt*64 + wid*16;
    int c0=ct*96;
    int lr=l&15, lk=(l>>4)*8;
    const short* ap = Xb + (size_t)(r0+lr)*KIN + lk;
    const short* bp = Wb + (size_t)(c0+lr)*KIN + lk;
    f32x4 acc[6];
    #pragma unroll
    for (int f=0;f<6;f++) acc[f]=(f32x4){0.f,0.f,0.f,0.f};
    for (int ks=0;ks<9;ks++){
        bf16x8 a = *(const bf16x8*)(ap + ks*32);
        #pragma unroll
        for (int f=0;f<6;f++){
            bf16x8 b = *(const bf16x8*)(bp + (size_t)f*16*KIN + ks*32);
            acc[f] = __builtin_amdgcn_mfma_f32_16x16x32_bf16(a,b,acc[f],0,0,0);
        }
    }
    int orow = r0 + (l>>4)*4;
    int ocol = c0 + lr;
    #pragma unroll
    for (int f=0;f<6;f++){
        #pragma unroll
        for (int qq=0;qq<4;qq++){
            Yb[(size_t)(orow+qq)*COLS + ocol + 16*f] = f2b(acc[f][qq]);
        }
    }
}

// ---------------- kA_post: 4 rows/block, bf16 content/gated_v out ----------------
__global__ __launch_bounds__(256,4) void kA_post(const short* Yb,const float* bias_cat,
        const float* sg_w2,const float* sg_b2,
        const float* hop_w2T,const float* hop_b2,const float* pos_phases,
        short* contentb,short* gatedvb,float* ctx,float* key_ph,
        float* store_gate,float* coef_mem){
    __shared__ float yb[4][1448];
    __shared__ float red[4][32];
    __shared__ float offb[4][136];
    __shared__ float scl[4][4];
    __shared__ float sgvv[4];
    int t=threadIdx.x;
    int r0=blockIdx.x*4;
    {
        const ushort4* Yu4 = (const ushort4*)(Yb) + (size_t)r0*360;
        #pragma unroll
        for (int i=0;i<6;i++){
            int chunk=i*256+t;
            if (chunk<1440){
                int r=chunk/360, c=(chunk%360)*4;
                ushort4 s4 = Yu4[chunk];
                float4 bc = *(const float4*)&bias_cat[c];
                yb[r][c+0]=b2f(s4.x)+bc.x;
                yb[r][c+1]=b2f(s4.y)+bc.y;
                yb[r][c+2]=b2f(s4.z)+bc.z;
                yb[r][c+3]=b2f(s4.w)+bc.w;
            }
        }
    }
    __syncthreads();
    #pragma unroll
    for (int r=0;r<4;r++){
        contentb[(size_t)(r0+r)*DD+t] = f2b(yb[r][t]);
        ctx[(size_t)(r0+r)*DD+t]      = yb[r][512+t];
    }
    #pragma unroll
    for (int j=0;j<8;j++){
        int idx=j*256+t, r=idx>>9, g=idx&511;
        yb[r][928+g] = gelu_f(yb[r][928+g]);
    }
    if (t<128){
        int r=t>>5, j=t&31;
        float s=0.f;
        #pragma unroll
        for (int k=0;k<4;k++){
            int jj=j+32*k;
            s += gelu_f(yb[r][800+jj])*sg_w2[jj];
        }
        red[r][j]=s;
        key_ph[(size_t)(r0+r)*PP+j] = tanhf(yb[r][768+j])*PI_F;
    }
    __syncthreads();
    if (t<128){
        int r=t>>5;
        float s=red[r][t&31];
        #pragma unroll
        for (int off=16;off>=1;off>>=1) s += __shfl_down(s,off,32);
        if ((t&31)==0){
            float g=sigm_f(s+sg_b2[0]);
            sgvv[r]=g;
            store_gate[r0+r]=g;
        }
    }
    for (int sIdx=t; sIdx<528; sIdx+=256){
        int r=sIdx/132, o=sIdx%132, h=o/33;
        const float* yh=&yb[r][928+h*128];
        float a0=0.f,a1=0.f,a2=0.f,a3=0.f;
        #pragma unroll 8
        for (int k=0;k<128;k+=4){
            a0 += hop_w2T[(size_t)(k+0)*132+o]*yh[k+0];
            a1 += hop_w2T[(size_t)(k+1)*132+o]*yh[k+1];
            a2 += hop_w2T[(size_t)(k+2)*132+o]*yh[k+2];
            a3 += hop_w2T[(size_t)(k+3)*132+o]*yh[k+3];
        }
        offb[r][o]=a0+a1+a2+a3+hop_b2[o];
    }
    __syncthreads();
    #pragma unroll
    for (int r=0;r<4;r++) gatedvb[(size_t)(r0+r)*DD+t]=f2b(yb[r][256+t]*sgvv[r]);
    if (t<16){
        int r=t>>2, h=t&3;
        const float c01=0.99500416527802576610f;  // cos(0.1)
        const float c02=0.98006657784124163112f;  // cos(0.2)
        float ww=sigm_f(offb[r][h*33+32])*2.0f+0.1f;
        float iw=1.0f/(ww*ww+1e-6f);
        float w1=expf(-0.5f*iw);
        float w2=expf(-2.0f*iw);
        float tot=1.0f+2.0f*w1+2.0f*w2;
        float Wc =1.0f+2.0f*w1*c01+2.0f*w2*c02;
        scl[r][h]=Wc/((tot+1e-6f)*5.65685424949238019520f*4.0f); // /(sqrt(P)*H)
    }
    __syncthreads();
    if (t<128){
        int r=t>>5, p=t&31;
        int l=(r0+r)%LL;
        float ppv=pos_phases[l*PP+p];
        float ca=0.f, sb=0.f;
        #pragma unroll
        for (int h=0;h<4;h++){
            float center=tanhf(offb[r][h*33+p])*PI_F;
            float ang=ppv+center;
            float sc=scl[r][h];
            ca+=sc*cosf(ang);
            sb+=sc*sinf(ang);
        }
        coef_mem[(size_t)(r0+r)*PX+p]=ca;
        coef_mem[(size_t)(r0+r)*PX+32+p]=sb;
    }
}

// ---------------- k3a: ctx chunk sums ----------------
__global__ void k3a_ctxsum(const float* ctx,float* ctxcs){
    int t=threadIdx.x;
    int bi=blockIdx.x;
    int c=bi%NC, b=bi/NC;
    float s=0.f;
    for (int i=0;i<CC;i++) s += ctx[((size_t)b*LL + c*CC + i)*DD + t];
    ctxcs[(size_t)(b*NC+c)*DD + t] = s;
}
// ---------------- k3c: ctx_avg (reg-ILP scan; writes bf16 into Xin2b) ----------------
__global__ void k3c_ctxavg(const float* ctx,const float* ctxcs,short* Xin2b){
    int t=threadIdx.x;
    int bi=blockIdx.x;
    int c=bi%NC, b=bi/NC;
    float run=0.f;
    for (int cc=0;cc<c;cc++) run += ctxcs[(size_t)(b*NC+cc)*DD+t];
    float v[CC];
    #pragma unroll
    for (int i=0;i<CC;i++) v[i]=ctx[((size_t)b*LL + c*CC + i)*DD + t];
    #pragma unroll
    for (int i=0;i<CC;i++){
        int l = c*CC+i;
        run += v[i];
        Xin2b[((size_t)b*LL+l)*512 + 256 + t] = f2b(run/(float)(l+1));
    }
}

// ---------------- kmid: k3d1 (blocks 0..255) + kgate (blocks 256..319) ----------------
__global__ __launch_bounds__(256) void kmid(const short* Xin2b,const short* kvw1b,
        const float* kv_b1, short* Hb,
        const float* store_gate,const float* key_ph,float* coefkv){
    __shared__ float sh[2048];
    __shared__ float red[256];
    __shared__ float rsgS[64];
    int t=threadIdx.x;
    if (blockIdx.x < 256){
        // k3d1: kv MLP layer 1 (MFMA) -> gelu -> bf16 Hb
        int wid=t>>6, l=t&63;
        int q=blockIdx.x;
        int nt=q&3, mt=q>>2;
        int r0=mt*64 + wid*16;
        int c0=nt*64;
        int lr=l&15, lk=(l>>4)*8;
        const short* ap = Xin2b + (size_t)(r0+lr)*512 + lk;
        const short* bp = kvw1b + (size_t)(c0+lr)*512 + lk;
        f32x4 acc[4];
        #pragma unroll
        for (int f=0;f<4;f++) acc[f]=(f32x4){0.f,0.f,0.f,0.f};
        for (int ks=0;ks<16;ks++){
            bf16x8 a = *(const bf16x8*)(ap + ks*32);
            #pragma unroll
            for (int f=0;f<4;f++){
                bf16x8 b = *(const bf16x8*)(bp + (size_t)f*16*512 + ks*32);
                acc[f] = __builtin_amdgcn_mfma_f32_16x16x32_bf16(a,b,acc[f],0,0,0);
            }
        }
        int orow = r0 + (l>>4)*4;
        #pragma unroll
        for (int f=0;f<4;f++){
            int oc = c0 + lr + 16*f;
            float bias = kv_b1[oc];
            #pragma unroll
            for (int qq=0;qq<4;qq++){
                Hb[(size_t)(orow+qq)*256 + oc] = f2b(gelu_f(acc[f][qq]+bias));
            }
        }
        return;
    }
    // kgate
    int q=blockIdx.x-256;
    int c=q&31, b=q>>5;
    int n=(c+1)*CC;
    for (int i=t;i<n;i+=256) sh[i]=store_gate[(size_t)b*LL+i];
    __syncthreads();
    float p=0.f;
    for (int i=t;i<c*CC;i+=256) p+=sh[i];
    red[t]=p;
    __syncthreads();
    for (int off=128;off>=1;off>>=1){
        if (t<off) red[t]+=red[t+off];
        __syncthreads();
    }
    float S0=red[0];
    if (t<64){
        float s=sh[c*CC+t];
        #pragma unroll
        for (int off=1;off<64;off<<=1){
            float v=__shfl_up(s,off);
            if (t>=off) s+=v;
        }
        rsgS[t]=rsqrtf(fmaxf(S0+s,1.0f)*32.0f);
    }
    __syncthreads();
    #pragma unroll
    for (int j=0;j<8;j++){
        int g2=t+j*256;             // 64 rows * 32 p
        int l=g2>>5, pp=g2&31;
        float a=key_ph[((size_t)b*LL + c*CC + l)*PP + pp];
        float rv=rsgS[l];
        coefkv[((size_t)b*LL + c*CC + l)*PX + pp]      = cosf(a)*rv;
        coefkv[((size_t)b*LL + c*CC + l)*PX + 32 + pp] = sinf(a)*rv;
    }
}

// ---------------- k3d2: kv MLP layer 2 (MFMA) -> tanh -> cos/sin w2kv ----------------
__global__ __launch_bounds__(256) void k3d2(const short* Hb,const short* kvw2b,
        const float* kv_b2, float* w2kv){
    int t=threadIdx.x;
    int wid=t>>6, l=t&63;
    int mt=blockIdx.x;             // 64 blocks
    int r0=mt*64 + wid*16;
    int lr=l&15, lk=(l>>4)*8;
    const short* ap = Hb + (size_t)(r0+lr)*256 + lk;
    const short* bp = kvw2b + (size_t)lr*256 + lk;
    f32x4 acc0=(f32x4){0.f,0.f,0.f,0.f};
    f32x4 acc1=(f32x4){0.f,0.f,0.f,0.f};
    for (int ks=0;ks<8;ks++){
        bf16x8 a  = *(const bf16x8*)(ap + ks*32);
        bf16x8 b0 = *(const bf16x8*)(bp + ks*32);
        bf16x8 b1 = *(const bf16x8*)(bp + (size_t)16*256 + ks*32);
        acc0 = __builtin_amdgcn_mfma_f32_16x16x32_bf16(a,b0,acc0,0,0,0);
        acc1 = __builtin_amdgcn_mfma_f32_16x16x32_bf16(a,b1,acc1,0,0,0);
    }
    int orow=r0+(l>>4)*4;
    #pragma unroll
    for (int f=0;f<2;f++){
        int p = lr + 16*f;
        float bias = kv_b2[p];
        f32x4 av = f? acc1:acc0;
        #pragma unroll
        for (int qq=0;qq<4;qq++){
            float sp=tanhf(av[qq]+bias)*PI_F;
            w2kv[(size_t)(orow+qq)*PX + p]    = cosf(sp);
            w2kv[(size_t)(orow+qq)*PX + 32+p] = sinf(sp);
        }
    }
}

// ---------------- k4: per-chunk outer-product sums (d-split, bf16 val, both inst) ----------------
__global__ __launch_bounds__(256) void k4_chunksum(
        const short* valA,const float* w2A,int w2bA,
        const short* valB,const float* w2B,int w2bB,
        float* CS){
    __shared__ float w2s[CC][PX];    // 16 KB
    int t=threadIdx.x, q=blockIdx.x;
    int dq=q&3, c=(q>>2)&31, b=(q>>7)&1, inst=q>>8;
    const short* val = inst? valB:valA;
    const float* w2  = inst? w2B:w2A;
    int w2b          = inst? w2bB:w2bA;
    for (int i=0;i<16;i++){
        int idx=i*256+t;
        int l=idx>>6, p=idx&63;
        w2s[l][p]=w2[(size_t)w2b*b + (size_t)(c*CC+l)*PX + p];
    }
    __syncthreads();
    int d=t&63, pg=t>>6;
    float acc[16];
    #pragma unroll
    for (int j=0;j<16;j++) acc[j]=0.f;
    const short* vp = val + ((size_t)b*LL + c*CC)*DD + dq*64 + d;
    for (int l=0;l<CC;l++){
        float v = b2f((unsigned short)vp[(size_t)l*DD]);
        const float4* wr=(const float4*)&w2s[l][pg*16];
        #pragma unroll
        for (int k=0;k<4;k++){
            float4 w=wr[k];
            acc[4*k]   += w.x*v;
            acc[4*k+1] += w.y*v;
            acc[4*k+2] += w.z*v;
            acc[4*k+3] += w.w*v;
        }
    }
    float* cp = CS + (((size_t)(inst*BB+b)*NC + c)*PX + pg*16)*DD + dq*64 + d;
    #pragma unroll
    for (int j=0;j<16;j++) cp[(size_t)j*DD]=acc[j];
}

// ---------------- k5: exclusive prefix over chunks -> bf16 PFXb (ILP loads) ----------------
__global__ void k5_prefix(const float* CS,short* PFXb){
    int g=blockIdx.x*256+threadIdx.x;   // 2*BB*PX*DD = 65536 threads
    int d=g&255, p2=(g>>8)&63, b=(g>>14)&1, inst=g>>15;
    size_t base=(((size_t)(inst*BB+b)*NC)*PX+p2)*DD+d;
    float v[NC];
    #pragma unroll
    for (int c=0;c<NC;c++) v[c]=CS[base+(size_t)c*PX*DD];
    float run=0.f;
    #pragma unroll
    for (int c=0;c<NC;c++){
        PFXb[base+(size_t)c*PX*DD]=f2b(run);
        run+=v[c];
    }
}

// ---------------- k6: prefix-GEMM + diagonal causal tile (d-split, bf16 val/pfx) ----------------
__global__ __launch_bounds__(256) void k6_attn(
        const float* coefA,const float* w2A,int w2bA,const short* valA,float* outA,
        const float* coefB,const float* w2B,int w2bB,const short* valB,float* outB,
        const short* PFXb){
    __shared__ float coefs[CC][PX+1];
    __shared__ float w2s[CC][PX];
    __shared__ float S[CC][CC+1];
    int t=threadIdx.x, q=blockIdx.x;
    int dq=q&3, qc=(q>>2)&31, b=(q>>7)&1, inst=q>>8;
    const float* coef = inst? coefB:coefA;
    const float* w2   = inst? w2B:w2A;
    int w2b           = inst? w2bB:w2bA;
    const short* val  = inst? valB:valA;
    float* out        = inst? outB:outA;
    int d0 = dq*64;
    for (int i=0;i<16;i++){
        int idx=i*256+t;
        int l=idx>>6, p=idx&63;
        coefs[l][p]=coef[((size_t)b*LL + qc*CC + l)*PX + p];
        w2s[l][p]  =w2[(size_t)w2b*b + (size_t)(qc*CC+l)*PX + p];
    }
    __syncthreads();
    // diagonal score tile S[l][lp], causal lp<=l
    {
        int l=t&63, lpb=(t>>6)*16;
        float cf[PX];
        #pragma unroll
        for (int p=0;p<PX;p++) cf[p]=coefs[l][p];
        for (int qq=0;qq<16;qq++){
            int lp=lpb+qq;
            float s=0.f;
            if (lp<=l){
                const float4* wr=(const float4*)&w2s[lp][0];
                #pragma unroll
                for (int k=0;k<16;k++){
                    float4 w=wr[k];
                    s += w.x*cf[4*k]+w.y*cf[4*k+1]+w.z*cf[4*k+2]+w.w*cf[4*k+3];
                }
            }
            S[l][lp]=s;
        }
    }
    __syncthreads();
    // prefix-GEMM (previous chunks, bf16 pfx) + in-chunk PV
    {
        int d=t&63, lq=t>>6;             // 4 q-groups x 16 rows, 64 d each
        float acc[16];
        #pragma unroll
        for (int i=0;i<16;i++) acc[i]=0.f;
        const short* pfx = PFXb + (((size_t)(inst*BB+b)*NC + qc)*PX)*DD + d0 + d;
        for (int p=0;p<PX;p++){
            float pf = b2f((unsigned short)pfx[(size_t)p*DD]);
            #pragma unroll
            for (int i=0;i<16;i++) acc[i] += coefs[lq*16+i][p]*pf;
        }
        const short* vptr = val + ((size_t)b*LL + qc*CC)*DD + d0 + d;
        int kmax = lq*16+16;
        for (int lp=0; lp<kmax; lp++){
            float v = b2f((unsigned short)vptr[(size_t)lp*DD]);
            #pragma unroll
            for (int i=0;i<16;i++) acc[i] += S[lq*16+i][lp]*v;
        }
        float* op = out + ((size_t)b*LL + qc*CC + lq*16)*DD + d0 + d;
        #pragma unroll
        for (int i=0;i<16;i++) op[(size_t)i*DD] = acc[i];
    }
}

// ---------------- k7: LN + MFMA output GEMM + residual, write FLOAT32 ----------------
__global__ __launch_bounds__(256) void k7_final(const float* comb,const float* kvout,
        const float* x,const float* ln_g,const float* ln_b,const short* w_outb,const float* b_out,
        float* out){
    __shared__ float cb[16][260];
    __shared__ short Ab[16][264];
    __shared__ float red[16][32];
    __shared__ float mvm[16][2];
    int t=threadIdx.x, r0=blockIdx.x*16;
    #pragma unroll
    for (int i=0;i<16;i++){
        int idx=i*256+t;
        int r=idx>>8, c=idx&255;
        cb[r][c]=comb[(size_t)(r0+r)*DD+c]+kvout[(size_t)(r0+r)*DD+c];
    }
    __syncthreads();
    {
        int r=t>>4, j=t&15;
        float s=0.f,s2=0.f;
        #pragma unroll
        for (int k=0;k<16;k++){
            float v=cb[r][j+16*k];
            s+=v; s2+=v*v;
        }
        red[r][j]=s; red[r][16+j]=s2;
    }
    __syncthreads();
    if (t<16){
        float s=0.f,s2=0.f;
        #pragma unroll
        for (int j=0;j<16;j++){ s+=red[t][j]; s2+=red[t][16+j]; }
        float mu=s/256.f;
        float var=s2/256.f-mu*mu;
        mvm[t][0]=mu; mvm[t][1]=rsqrtf(var+1e-5f);
    }
    __syncthreads();
    #pragma unroll
    for (int i=0;i<16;i++){
        int idx=i*256+t;
        int r=idx>>8, c=idx&255;
        Ab[r][c]=f2b((cb[r][c]-mvm[r][0])*mvm[r][1]*ln_g[c]+ln_b[c]);
    }
    __syncthreads();
    int wid=t>>6, l=t&63;
    int lr=l&15, lk=(l>>4)*8;
    f32x4 acc[4];
    #pragma unroll
    for (int f=0;f<4;f++) acc[f]=(f32x4){0.f,0.f,0.f,0.f};
    for (int ks=0;ks<8;ks++){
        bf16x8 a = *(const bf16x8*)&Ab[lr][lk+ks*32];
        #pragma unroll
        for (int f=0;f<4;f++){
            bf16x8 bv = *(const bf16x8*)(w_outb + (size_t)(wid*64+f*16+lr)*256 + lk + ks*32);
            acc[f] = __builtin_amdgcn_mfma_f32_16x16x32_bf16(a,bv,acc[f],0,0,0);
        }
    }
    int orow = r0 + (l>>4)*4;
    #pragma unroll
    for (int f=0;f<4;f++){
        int oc = wid*64 + f*16 + lr;
        float bo = b_out[oc];
        #pragma unroll
        for (int qq=0;qq<4;qq++){
            out[(size_t)(orow+qq)*DD + oc] = x[(size_t)(orow+qq)*DD + oc] + acc[f][qq] + bo;
        }
    }
}

extern "C" void kernel_launch(void* const* d_in, const int* in_sizes, int n_in,
                              void* d_out, int out_size, void* d_ws, size_t ws_size,
                              hipStream_t stream){
    (void)in_sizes; (void)n_in; (void)out_size; (void)ws_size;
    const float* x         =(const float*)d_in[0];
    const float* pos_phases=(const float*)d_in[1];
    const float* w_content =(const float*)d_in[2];
    const float* b_content =(const float*)d_in[3];
    const float* hop_w1    =(const float*)d_in[4];
    const float* hop_b1    =(const float*)d_in[5];
    const float* hop_w2    =(const float*)d_in[6];
    const float* hop_b2    =(const float*)d_in[7];
    const float* w_cpe     =(const float*)d_in[8];
    const float* b_cpe     =(const float*)d_in[9];
    const float* w_val     =(const float*)d_in[10];
    const float* b_val     =(const float*)d_in[11];
    const float* w_ctx     =(const float*)d_in[12];
    const float* b_ctx     =(const float*)d_in[13];
    const float* kv_w1     =(const float*)d_in[14];
    const float* kv_b1     =(const float*)d_in[15];
    const float* kv_w2     =(const float*)d_in[16];
    const float* kv_b2     =(const float*)d_in[17];
    const float* sg_w1     =(const float*)d_in[18];
    const float* sg_b1     =(const float*)d_in[19];
    const float* sg_w2     =(const float*)d_in[20];
    const float* sg_b2     =(const float*)d_in[21];
    const float* ln_g      =(const float*)d_in[22];
    const float* ln_b      =(const float*)d_in[23];
    const float* w_out     =(const float*)d_in[24];
    const float* b_out     =(const float*)d_in[25];

    float* ws=(float*)d_ws;
    size_t o=0;
    short* W_catb  =(short*)(ws+o); o+=(size_t)COLS*KIN/2;
    short* Xb      =(short*)(ws+o); o+=(size_t)NROW*KIN/2;
    short* kvw1b   =(short*)(ws+o); o+=(size_t)256*512/2;
    short* kvw2b   =(short*)(ws+o); o+=(size_t)32*256/2;
    short* w_outb  =(short*)(ws+o); o+=(size_t)256*256/2;
    short* Hb      =(short*)(ws+o); o+=(size_t)NROW*256/2;
    short* contentb=(short*)(ws+o); o+=(size_t)NROW*DD/2;
    short* gatedvb =(short*)(ws+o); o+=(size_t)NROW*DD/2;
    short* PFXb    =(short*)(ws+o); o+=(size_t)2*BB*NC*PX*DD/2;
    float* bias_cat=ws+o; o+=COLS;
    float* hop_w2T =ws+o; o+=(size_t)128*132;
    float* w2mem   =ws+o; o+=(size_t)LL*PX;
    float* ctx     =ws+o; o+=(size_t)NROW*DD;      // dead after k3c -> comb
    float* xin2_kv =ws+o; o+=(size_t)NROW*DD;      // Xin2b (bf16) then kvout (f32)
    float* key_ph  =ws+o; o+=(size_t)NROW*PP;
    float* store_gate=ws+o; o+=NROW;
    float* coef_mem=ws+o; o+=(size_t)NROW*PX;
    float* coefkv  =ws+o; o+=(size_t)NROW*PX;
    float* w2kv    =ws+o; o+=(size_t)NROW*PX;
    float* ctxcs   =ws+o; o+=(size_t)BB*NC*DD;
    float* CS      =ws+o; o+=(size_t)2*BB*NC*PX*DD;  // 16.8 MB; Yb (bf16) aliases it
    short* Yb      =(short*)CS;          // Yb dead before k4 writes CS
    short* Xin2b   =(short*)xin2_kv;     // written kprep/k3c, read kmid (before k6)
    float* comb  = ctx;
    float* kvout = xin2_kv;              // written k6, read k7

    int prep_total = COLS*KIN + COLS + LL*PP + 256*512 + 32*256 + 128*132 + 256*256 + NROW*KIN;
    kprep<<<(prep_total+255)/256,256,0,stream>>>(
                                 w_content,w_val,w_ctx,w_cpe,sg_w1,hop_w1,
                                 b_content,b_val,b_ctx,b_cpe,sg_b1,hop_b1,
                                 pos_phases,kv_w1,kv_w2,hop_w2,w_out,x,
                                 W_catb,bias_cat,w2mem,kvw1b,kvw2b,hop_w2T,w_outb,Xb,Xin2b);
    kA_gemm<<<960,256,0,stream>>>(Xb,W_catb,Yb);
    kA_post<<<NROW/4,256,0,stream>>>(Yb,bias_cat,sg_w2,sg_b2,hop_w2T,hop_b2,pos_phases,
                                     contentb,gatedvb,ctx,key_ph,store_gate,coef_mem);
    k3a_ctxsum<<<BB*NC,256,0,stream>>>(ctx,ctxcs);
    k3c_ctxavg<<<BB*NC,256,0,stream>>>(ctx,ctxcs,Xin2b);
    kmid<<<256+BB*NC,256,0,stream>>>(Xin2b,kvw1b,kv_b1,Hb,store_gate,key_ph,coefkv);
    k3d2<<<64,256,0,stream>>>(Hb,kvw2b,kv_b2,w2kv);
    k4_chunksum<<<2*BB*NC*4,256,0,stream>>>(contentb,w2mem,0,
                                            gatedvb,w2kv,LL*PX,CS);
    k5_prefix<<<2*BB*PX*DD/256,256,0,stream>>>(CS,PFXb);
    k6_attn<<<2*BB*NC*4,256,0,stream>>>(coef_mem,w2mem,0,contentb,comb,
                                        coefkv,w2kv,LL*PX,gatedvb,kvout,PFXb);
    k7_final<<<NROW/16,256,0,stream>>>(comb,kvout,x,ln_g,ln_b,w_outb,b_out,
                                       (float*)d_out);
}